// Round 8
// baseline (267.332 us; speedup 1.0000x reference)
//
#include <hip/hip_runtime.h>

#define NN 50000
#define NE 400000
#define FD 64
#define NH 2
#define HF 128   // H * F
#define NB 8     // nodes per block in node_transform
#define SCAN_NB ((NN + 255) / 256)   // 196 blocks for two-level scan
#define POOL_BLOCKS 512

__device__ __forceinline__ float lrelu(float x, float s) { return x > 0.f ? x : s * x; }

// ---- bf16 helpers: RNE pack, exact unpack ----
__device__ __forceinline__ unsigned short f2bf(float f) {
    unsigned u = __float_as_uint(f);
    return (unsigned short)((u + 0x7FFFu + ((u >> 16) & 1u)) >> 16);
}
__device__ __forceinline__ float2 bf2f(unsigned u) {
    return make_float2(__uint_as_float(u << 16), __uint_as_float(u & 0xFFFF0000u));
}
__device__ __forceinline__ float4 bfx4(uint2 l) {
    const float2 a = bf2f(l.x), b = bf2f(l.y);
    return make_float4(a.x, a.y, b.x, b.y);
}

// ================= CSR build (once per launch) =================
__global__ void count_deg(const int* __restrict__ ei, int* __restrict__ deg) {
    const int t = blockIdx.x * blockDim.x + threadIdx.x;
    if (t < NE) atomicAdd(&deg[ei[NE + t]], 1);
}

__global__ void block_sums(const int* __restrict__ deg, int* __restrict__ bsum) {
    __shared__ int s[4];
    const int t = threadIdx.x;
    const int i = blockIdx.x * 256 + t;
    int v = (i < NN) ? deg[i] : 0;
#pragma unroll
    for (int o = 32; o; o >>= 1) v += __shfl_xor(v, o);
    if ((t & 63) == 0) s[t >> 6] = v;
    __syncthreads();
    if (t == 0) bsum[blockIdx.x] = s[0] + s[1] + s[2] + s[3];
}

__global__ void scan_bsums(const int* __restrict__ bsum, int* __restrict__ boff) {
    __shared__ int s[256];
    const int t = threadIdx.x;  // 256 >= SCAN_NB
    s[t] = (t < SCAN_NB) ? bsum[t] : 0;
    __syncthreads();
    for (int o = 1; o < 256; o <<= 1) {
        int u = (t >= o) ? s[t - o] : 0;
        __syncthreads();
        s[t] += u;
        __syncthreads();
    }
    boff[t] = (t == 0) ? 0 : s[t - 1];   // exclusive block offsets
}

__global__ void write_base(const int* __restrict__ deg, const int* __restrict__ boff,
                           int* __restrict__ base, int2* __restrict__ rng,
                           int* __restrict__ cursor) {
    __shared__ int s[256];
    const int t = threadIdx.x;
    const int i = blockIdx.x * 256 + t;
    const int v = (i < NN) ? deg[i] : 0;
    s[t] = v;
    __syncthreads();
    for (int o = 1; o < 256; o <<= 1) {
        int u = (t >= o) ? s[t - o] : 0;
        __syncthreads();
        s[t] += u;
        __syncthreads();
    }
    const int off = boff[blockIdx.x];
    if (i < NN) {
        const int b = off + s[t] - v;
        base[i] = b;                        // exclusive prefix (for scatter)
        rng[i] = make_int2(b, b + v);       // [start, end) single 8B load
        cursor[i] = 0;                      // fused cursor init
    }
}

__global__ void scatter_edges(const int* __restrict__ ei, const float* __restrict__ ea,
                              const int* __restrict__ base, int* __restrict__ cursor,
                              int2* __restrict__ csr) {
    const int t = blockIdx.x * blockDim.x + threadIdx.x;
    if (t >= NE) return;
    const int d = ei[NE + t];
    const int p = atomicAdd(&cursor[d], 1);
    const int i = base[d] + p;
    csr[i] = make_int2(ei[t], __float_as_int(ea[t]));
}

// ---- per-layer: xl(bf16) = hin@Wl+bl, xr(bf16) = hin@Wr+br ----
__global__ void node_transform(const float* __restrict__ hin,
                               const float* __restrict__ Wl, const float* __restrict__ bl,
                               const float* __restrict__ Wr, const float* __restrict__ br,
                               unsigned short* __restrict__ xlb,
                               unsigned short* __restrict__ xrb) {
    __shared__ float s[NB][FD];
    const int n0 = blockIdx.x * NB;
    const int t = threadIdx.x;  // 128 threads, t = output column j
    for (int i = t; i < NB * FD; i += 128) {
        int ni = n0 + (i >> 6);
        s[i >> 6][i & 63] = (ni < NN) ? hin[(size_t)ni * FD + (i & 63)] : 0.f;
    }
    __syncthreads();
    float al[NB], ar[NB];
    const float bLv = bl[t], bRv = br[t];
#pragma unroll
    for (int i = 0; i < NB; ++i) { al[i] = bLv; ar[i] = bRv; }
#pragma unroll 4
    for (int k = 0; k < FD; ++k) {
        float wl = Wl[k * HF + t];
        float wr = Wr[k * HF + t];
#pragma unroll
        for (int i = 0; i < NB; ++i) {
            al[i] = fmaf(s[i][k], wl, al[i]);
            ar[i] = fmaf(s[i][k], wr, ar[i]);
        }
    }
#pragma unroll
    for (int i = 0; i < NB; ++i) {
        int n = n0 + i;
        if (n < NN) {
            xlb[(size_t)n * HF + t] = f2bf(al[i]);
            xrb[(size_t)n * HF + t] = f2bf(ar[i]);
        }
    }
}

// ---- one edge-slot update: dot, 16-lane reduce, defer-max accumulate ----
__device__ __forceinline__ void gat_edge(
    bool valid, float eav, uint2 l0, uint2 l1,
    const float4& we0, const float4& we1, const float4& aw0, const float4& aw1,
    const float4& xr0, const float4& xr1,
    float4& a0, float4& a1, float& d0, float& d1) {
    const float4 xls0 = bfx4(l0);
    const float4 xls1 = bfx4(l1);
    float p0, p1, t;
    t = lrelu(fmaf(eav, we0.x, xls0.x + xr0.x), 0.2f); p0 = t * aw0.x;
    t = lrelu(fmaf(eav, we0.y, xls0.y + xr0.y), 0.2f); p0 = fmaf(t, aw0.y, p0);
    t = lrelu(fmaf(eav, we0.z, xls0.z + xr0.z), 0.2f); p0 = fmaf(t, aw0.z, p0);
    t = lrelu(fmaf(eav, we0.w, xls0.w + xr0.w), 0.2f); p0 = fmaf(t, aw0.w, p0);
    t = lrelu(fmaf(eav, we1.x, xls1.x + xr1.x), 0.2f); p1 = t * aw1.x;
    t = lrelu(fmaf(eav, we1.y, xls1.y + xr1.y), 0.2f); p1 = fmaf(t, aw1.y, p1);
    t = lrelu(fmaf(eav, we1.z, xls1.z + xr1.z), 0.2f); p1 = fmaf(t, aw1.z, p1);
    t = lrelu(fmaf(eav, we1.w, xls1.w + xr1.w), 0.2f); p1 = fmaf(t, aw1.w, p1);
#pragma unroll
    for (int o = 8; o; o >>= 1) {
        p0 += __shfl_xor(p0, o);
        p1 += __shfl_xor(p1, o);
    }
    const float w0 = valid ? __expf(p0) : 0.f;
    const float w1 = valid ? __expf(p1) : 0.f;
    a0.x = fmaf(w0, xls0.x, a0.x);
    a0.y = fmaf(w0, xls0.y, a0.y);
    a0.z = fmaf(w0, xls0.z, a0.z);
    a0.w = fmaf(w0, xls0.w, a0.w);
    d0 += w0;
    a1.x = fmaf(w1, xls1.x, a1.x);
    a1.y = fmaf(w1, xls1.y, a1.y);
    a1.z = fmaf(w1, xls1.z, a1.z);
    a1.w = fmaf(w1, xls1.w, a1.w);
    d1 += w1;
}

// ---- fused per-node gather: 16 lanes/edge x 4 slots, 16 edges in flight ----
__global__ void gat_gather(const int2* __restrict__ rng, const int2* __restrict__ csr,
                           const unsigned short* __restrict__ xlb,
                           const unsigned short* __restrict__ xrb,
                           const float* __restrict__ We, const float* __restrict__ att,
                           const float* __restrict__ bias, float* __restrict__ hout) {
    const int wid = (blockIdx.x * blockDim.x + threadIdx.x) >> 6;
    const int lane = threadIdx.x & 63;
    if (wid >= NN) return;
    const int slot = lane >> 4;          // which of 4 edge-slots per group
    const int fo = (lane & 15) << 2;     // feature chunk [fo, fo+4)
    const float4 we0 = *(const float4*)(We + fo);
    const float4 we1 = *(const float4*)(We + 64 + fo);
    const float4 aw0 = *(const float4*)(att + fo);
    const float4 aw1 = *(const float4*)(att + 64 + fo);
    const float4 xr0 = bfx4(*(const uint2*)(xrb + (size_t)wid * HF + fo));
    const float4 xr1 = bfx4(*(const uint2*)(xrb + (size_t)wid * HF + 64 + fo));
    float d0 = 0.f, d1 = 0.f;
    float4 a0 = {0.f, 0.f, 0.f, 0.f}, a1 = {0.f, 0.f, 0.f, 0.f};
    const int2 r = rng[wid];
    const int e0 = r.x, e1 = r.y;

    for (int eb = e0; eb < e1; eb += 16) {
        int2 se[4];
        uint2 L0[4], L1[4];
        bool v[4];
        // phase 1: all csr loads in flight
#pragma unroll
        for (int g = 0; g < 4; ++g) {
            const int my = eb + 4 * g + slot;
            v[g] = my < e1;
            se[g] = csr[v[g] ? my : e0];
        }
        // phase 2: all 16 xl loads in flight
#pragma unroll
        for (int g = 0; g < 4; ++g) {
            const unsigned short* p = xlb + (size_t)se[g].x * HF + fo;
            L0[g] = *(const uint2*)p;
            L1[g] = *(const uint2*)(p + 64);
        }
        // phase 3: compute
#pragma unroll
        for (int g = 0; g < 4; ++g)
            gat_edge(v[g], __int_as_float(se[g].y), L0[g], L1[g],
                     we0, we1, aw0, aw1, xr0, xr1, a0, a1, d0, d1);
    }

    // merge the 4 slots: plain sum reduce over offsets 16, 32
#pragma unroll
    for (int o = 16; o <= 32; o <<= 1) {
        d0 += __shfl_xor(d0, o);
        d1 += __shfl_xor(d1, o);
        a0.x += __shfl_xor(a0.x, o); a0.y += __shfl_xor(a0.y, o);
        a0.z += __shfl_xor(a0.z, o); a0.w += __shfl_xor(a0.w, o);
        a1.x += __shfl_xor(a1.x, o); a1.y += __shfl_xor(a1.y, o);
        a1.z += __shfl_xor(a1.z, o); a1.w += __shfl_xor(a1.w, o);
    }

    if (slot == 0) {
        const float i0 = d0 > 0.f ? 1.f / d0 : 0.f;
        const float i1 = d1 > 0.f ? 1.f / d1 : 0.f;
        const float4 bv = *(const float4*)(bias + fo);
        float4 rr;
        rr.x = lrelu(fmaf(0.5f, fmaf(a0.x, i0, a1.x * i1), bv.x), 0.01f);
        rr.y = lrelu(fmaf(0.5f, fmaf(a0.y, i0, a1.y * i1), bv.y), 0.01f);
        rr.z = lrelu(fmaf(0.5f, fmaf(a0.z, i0, a1.z * i1), bv.z), 0.01f);
        rr.w = lrelu(fmaf(0.5f, fmaf(a0.w, i0, a1.w * i1), bv.w), 0.01f);
        *(float4*)(hout + (size_t)wid * FD + fo) = rr;
    }
}

// ---- fused gate + weighted pooling (defer-max: gate exp cancels in a/Σe) ----
__global__ void pool_kernel(const float* __restrict__ x, const float* __restrict__ h1,
                            const float* __restrict__ h2, const float* __restrict__ gw,
                            const float* __restrict__ gb, float* __restrict__ pooled) {
    __shared__ float sp[193];
    const int t = threadIdx.x;
    if (t < 193) sp[t] = 0.f;
    __syncthreads();
    const int lane = t & 63;
    const int wid = (blockIdx.x * blockDim.x + t) >> 6;
    const int nw = (POOL_BLOCKS * 256) >> 6;
    const float w0 = gw[lane], w1 = gw[64 + lane], w2 = gw[128 + lane];
    const float gbv = gb[0];
    float p0 = 0.f, p1 = 0.f, p2 = 0.f, es = 0.f;
    for (int n = wid; n < NN; n += nw) {
        const size_t b = (size_t)n * FD + lane;
        const float xv = x[b], h1v = h1[b], h2v = h2[b];
        float v = xv * w0 + h1v * w1 + h2v * w2;
#pragma unroll
        for (int o = 32; o; o >>= 1) v += __shfl_xor(v, o);
        const float e = __expf(lrelu(v + gbv, 0.01f));   // uniform across lanes
        p0 = fmaf(e, xv, p0);
        p1 = fmaf(e, h1v, p1);
        p2 = fmaf(e, h2v, p2);
        es += e;
    }
    atomicAdd(&sp[lane], p0);
    atomicAdd(&sp[64 + lane], p1);
    atomicAdd(&sp[128 + lane], p2);
    if (lane == 0) atomicAdd(&sp[192], es);
    __syncthreads();
    if (t < 193) atomicAdd(pooled + t, sp[t]);
}

// ---- final tiny MLP: z(193) -> 96 -> 96 -> 2 ----
__global__ void mlp_kernel(const float* __restrict__ pooled, const float* __restrict__ pt,
                           const float* __restrict__ f1w, const float* __restrict__ f1b,
                           const float* __restrict__ f2w, const float* __restrict__ f2b,
                           const float* __restrict__ flw, const float* __restrict__ flb,
                           float* __restrict__ out) {
    __shared__ float z[193], z1[96], z2[96];
    const int t = threadIdx.x;  // 256
    const float inv = 1.f / pooled[192];
    for (int i = t; i < 192; i += 256) z[i] = pooled[i] * inv;
    if (t == 0) z[192] = pt[0];
    __syncthreads();
    if (t < 96) {
        float a = f1b[t];
        for (int k = 0; k < 193; ++k) a = fmaf(z[k], f1w[k * 96 + t], a);
        z1[t] = lrelu(a, 0.01f);
    }
    __syncthreads();
    if (t < 96) {
        float a = f2b[t];
        for (int k = 0; k < 96; ++k) a = fmaf(z1[k], f2w[k * 96 + t], a);
        z2[t] = lrelu(a, 0.01f);
    }
    __syncthreads();
    if (t < 2) {
        float a = flb[t];
        for (int k = 0; k < 96; ++k) a = fmaf(z2[k], flw[k * 2 + t], a);
        out[t] = a;
    }
}

extern "C" void kernel_launch(void* const* d_in, const int* in_sizes, int n_in,
                              void* d_out, int out_size, void* d_ws, size_t ws_size,
                              hipStream_t stream) {
    (void)in_sizes; (void)n_in; (void)out_size; (void)ws_size;
    const float* x    = (const float*)d_in[0];
    const int*   ei   = (const int*)d_in[1];
    const float* ea   = (const float*)d_in[2];
    const float* pt   = (const float*)d_in[3];
    const float* llw  = (const float*)d_in[5];
    const float* llb  = (const float*)d_in[6];
    const float* lrw  = (const float*)d_in[7];
    const float* lrb  = (const float*)d_in[8];
    const float* lew  = (const float*)d_in[9];
    const float* attw = (const float*)d_in[10];
    const float* gbias= (const float*)d_in[11];
    const float* gw   = (const float*)d_in[12];
    const float* gb   = (const float*)d_in[13];
    const float* f1w  = (const float*)d_in[14];
    const float* f1b  = (const float*)d_in[15];
    const float* f2w  = (const float*)d_in[16];
    const float* f2b  = (const float*)d_in[17];
    const float* flw  = (const float*)d_in[18];
    const float* flb  = (const float*)d_in[19];
    float* out = (float*)d_out;

    char* w = (char*)d_ws;
    unsigned short* xlb = (unsigned short*)w; w += (size_t)NN * HF * 2;
    unsigned short* xrb = (unsigned short*)w; w += (size_t)NN * HF * 2;
    float* h1 = (float*)w;         w += (size_t)NN * FD * 4;
    float* h2 = (float*)w;         w += (size_t)NN * FD * 4;
    int2* csr = (int2*)w;          w += (size_t)NE * 8;
    int* deg = (int*)w;            w += (size_t)NN * 4;
    int* csr_base = (int*)w;       w += (size_t)(NN + 1) * 4;
    int2* rng = (int2*)w;          w += (size_t)NN * 8;
    int* cursor = (int*)w;         w += (size_t)NN * 4;
    int* bsum = (int*)w;           w += (size_t)SCAN_NB * 4;
    int* boff = (int*)w;           w += 256 * 4;
    float* pooled = (float*)w;     w += 193 * 4;

    // ---- CSR build (edge structure shared by both layers) ----
    hipMemsetAsync(deg, 0, (size_t)NN * 4, stream);
    count_deg<<<(NE + 255) / 256, 256, 0, stream>>>(ei, deg);
    block_sums<<<SCAN_NB, 256, 0, stream>>>(deg, bsum);
    scan_bsums<<<1, 256, 0, stream>>>(bsum, boff);
    write_base<<<SCAN_NB, 256, 0, stream>>>(deg, boff, csr_base, rng, cursor);
    scatter_edges<<<(NE + 255) / 256, 256, 0, stream>>>(ei, ea, csr_base, cursor, csr);

    // ---- 2 GAT layers ----
    for (int p = 0; p < 2; ++p) {
        const float* hin = (p == 0) ? x : h1;
        float* hout = (p == 0) ? h1 : h2;
        node_transform<<<(NN + NB - 1) / NB, 128, 0, stream>>>(
            hin, llw + (size_t)p * FD * HF, llb + (size_t)p * HF,
            lrw + (size_t)p * FD * HF, lrb + (size_t)p * HF, xlb, xrb);
        gat_gather<<<(NN + 3) / 4, 256, 0, stream>>>(
            rng, csr, xlb, xrb,
            lew + (size_t)p * HF, attw + (size_t)p * HF,
            gbias + (size_t)p * FD, hout);
    }

    // ---- fused gate+pooling + MLP ----
    hipMemsetAsync(pooled, 0, 193 * 4, stream);
    pool_kernel<<<POOL_BLOCKS, 256, 0, stream>>>(x, h1, h2, gw, gb, pooled);
    mlp_kernel<<<1, 256, 0, stream>>>(pooled, pt, f1w, f1b, f2w, f2b, flw, flb, out);
}